// Round 7
// baseline (302.537 us; speedup 1.0000x reference)
//
#include <hip/hip_runtime.h>
#include <cstdint>

// GCN forward on MI355X (gfx950). f32 in/out; bf16 MFMA with fp32 accum;
// bf16 intermediates; 4-byte packed fixed-stride CSR (src:u16 | weight:bf16).
// Round 16: GEMM restructure — B operands read DIRECT from L2 (no LDS stage;
//   wave's frag reads fully consume 64B lines), A double-buffered in LDS
//   (2x8KB gemm1 / 2x16KB gemm2) with one __syncthreads per K-step (T3
//   minimum template). Removes the B-stage drain + halves barriers.
//   spmm: phase-2 B also direct-from-L2; gather batches deepened to 16.
// Chain (5): prep0 -> [bucketA || gemm1(f32 A)] -> csr_sort ->
//   spmm1+bias+relu+gemm2 -> spmm2+bias+log_softmax.

typedef unsigned short u16;
typedef unsigned int u32;
typedef unsigned long long u64;
typedef __attribute__((ext_vector_type(8))) short bf16x8;
typedef __attribute__((ext_vector_type(4))) float f32x4;

#define N_NODES 50000
#define N_EDGES 800000
#define NFEAT 512
#define NHID 256
#define NCLASS 64
#define CSTRIDE 64        // fixed CSR slots per node (max deg << 64)

#define NBUCK 196         // coarse buckets: dst>>8 (50000/256)
#define BCAP 5120         // bucket region capacity (mean 4096 + 16 sigma)
#define SCB 391           // bucket-scatter blocks: ceil(800000/2048)
#define GB1 782           // gemm1 blocks: ceil(50000/64)
#define GB2 391           // gemm2 blocks: ceil(50000/128)
#define PW1B 512          // W1T transpose blocks
#define PW2B 64           // W2T transpose blocks
#define FNB 3125          // fused spmm1+gemm2 blocks: 50000/16

__device__ __forceinline__ float bf2f(u16 h) {
    union { u32 u; float f; } c; c.u = ((u32)h) << 16; return c.f;
}
__device__ __forceinline__ u16 f2bf(float f) {
    union { float f; u32 u; } c; c.f = f;
    u32 u = c.u;
    return (u16)((u + 0x7fffu + ((u >> 16) & 1u)) >> 16);   // RNE
}
__device__ __forceinline__ u32 pk2(float a, float b) {
    return (u32)f2bf(a) | ((u32)f2bf(b) << 16);
}

// async global->LDS, 16B per lane; LDS dest = wave-uniform base + lane*16.
__device__ __forceinline__ void async16(const void* g, void* l) {
    __builtin_amdgcn_global_load_lds(
        (const __attribute__((address_space(1))) void*)(uintptr_t)g,
        (__attribute__((address_space(3))) void*)(uintptr_t)l, 16, 0, 0);
}

// ---------------- prep0: W1/W2 transpose+cvt + fill zeroing ----------------

__global__ __launch_bounds__(256) void prep0_kernel(
    const float* __restrict__ W1, u16* __restrict__ W1T,
    const float* __restrict__ W2, u16* __restrict__ W2T,
    int* __restrict__ fill) {
    int b = blockIdx.x;
    if (b < PW1B) {
        int idx = b * 256 + threadIdx.x;           // W1T[256][512]
        int n = idx >> 9, k = idx & 511;
        W1T[idx] = f2bf(W1[(size_t)k * NHID + n]);
    } else if (b < PW1B + PW2B) {
        int idx = (b - PW1B) * 256 + threadIdx.x;  // W2T[64][256]
        int n = idx >> 8, k = idx & 255;
        W2T[idx] = f2bf(W2[(size_t)k * NCLASS + n]);
    } else {
        if (threadIdx.x < NBUCK) fill[threadIdx.x] = 0;
    }
}

// ---------------- gemm1 body: S1[M,256] = cvt_bf16(x[M,512]) @ W1T[256][512]^T ----------------
// A double-buffered in LDS (2x4096 u16, XOR-swizzled); B frags DIRECT from
// global (L2-resident W1T; wave reads whole 64B lines). One barrier per K-step.

__device__ __forceinline__ void gemm1_body(const float* __restrict__ x,
                                           const u16* __restrict__ BT,
                                           u16* __restrict__ C, int M,
                                           int bid, u16* lds) {
    const int tid = threadIdx.x;
    const int wcol = tid >> 6, lane = tid & 63;     // WROWS=1, WCOLS=4
    const int lm = lane & 15, quad = lane >> 4;
    const int m0 = bid * 64;
    const int co0 = ((0 * 4 + quad) ^ (lm & 7)) * 8;
    const int co1 = ((1 * 4 + quad) ^ (lm & 7)) * 8;
    const int arow = tid >> 2;                      // staging row 0..63
    int gr = m0 + arow; if (gr > M - 1) gr = M - 1;
    const float* gpb = x + (size_t)gr * NFEAT + (tid & 3) * 16;
    const int ch0 = (2 * (tid & 3)) ^ (arow & 7);
    const int ch1 = (2 * (tid & 3) + 1) ^ (arow & 7);

    f32x4 acc[4][4];
    #pragma unroll
    for (int r = 0; r < 4; ++r)
        #pragma unroll
        for (int c = 0; c < 4; ++c) acc[r][c] = (f32x4){0.f, 0.f, 0.f, 0.f};

    // prologue: stage tile 0 into buffer 0
    {
        const float4* gp = (const float4*)gpb;
        float4 f0 = gp[0], f1 = gp[1], f2 = gp[2], f3 = gp[3];
        u32 p[8] = {pk2(f0.x, f0.y), pk2(f0.z, f0.w), pk2(f1.x, f1.y), pk2(f1.z, f1.w),
                    pk2(f2.x, f2.y), pk2(f2.z, f2.w), pk2(f3.x, f3.y), pk2(f3.z, f3.w)};
        *(int4*)(lds + arow * 64 + ch0 * 8) = *(int4*)&p[0];
        *(int4*)(lds + arow * 64 + ch1 * 8) = *(int4*)&p[4];
    }
    __syncthreads();

    for (int t = 0; t < 8; ++t) {
        u16* As = lds + (t & 1) * 4096;
        u16* An = lds + ((t + 1) & 1) * 4096;
        bool pf = (t + 1) < 8;
        float4 f0, f1, f2, f3;
        if (pf) {                                    // issue next-tile A loads early
            const float4* gp = (const float4*)(gpb + (t + 1) * 64);
            f0 = gp[0]; f1 = gp[1]; f2 = gp[2]; f3 = gp[3];
        }
        #pragma unroll
        for (int kk = 0; kk < 2; ++kk) {
            const int co = kk ? co1 : co0;
            bf16x8 af[4], bfv[4];
            #pragma unroll
            for (int rt = 0; rt < 4; ++rt)
                af[rt] = *(const bf16x8*)(As + (rt * 16 + lm) * 64 + co);
            #pragma unroll
            for (int ct = 0; ct < 4; ++ct) {
                int n = wcol * 64 + ct * 16 + lm;
                bfv[ct] = *(const bf16x8*)(BT + (size_t)n * NFEAT + t * 64 + kk * 32 + quad * 8);
            }
            #pragma unroll
            for (int rt = 0; rt < 4; ++rt)
                #pragma unroll
                for (int ct = 0; ct < 4; ++ct)
                    acc[rt][ct] = __builtin_amdgcn_mfma_f32_16x16x32_bf16(
                        af[rt], bfv[ct], acc[rt][ct], 0, 0, 0);
        }
        if (pf) {                                    // pack+write behind the MFMAs
            u32 p[8] = {pk2(f0.x, f0.y), pk2(f0.z, f0.w), pk2(f1.x, f1.y), pk2(f1.z, f1.w),
                        pk2(f2.x, f2.y), pk2(f2.z, f2.w), pk2(f3.x, f3.y), pk2(f3.z, f3.w)};
            *(int4*)(An + arow * 64 + ch0 * 8) = *(int4*)&p[0];
            *(int4*)(An + arow * 64 + ch1 * 8) = *(int4*)&p[4];
        }
        __syncthreads();
    }

    // epilogue: 2 half-column passes through the 16KB scratch (64x128)
    #pragma unroll
    for (int h = 0; h < 2; ++h) {
        if ((wcol >> 1) == h) {
            #pragma unroll
            for (int rt = 0; rt < 4; ++rt)
                #pragma unroll
                for (int ct = 0; ct < 4; ++ct) {
                    int col = wcol * 64 + ct * 16 + lm - h * 128;
                    #pragma unroll
                    for (int r = 0; r < 4; ++r)
                        lds[(rt * 16 + quad * 4 + r) * 128 + col] = f2bf(acc[rt][ct][r]);
                }
        }
        __syncthreads();
        #pragma unroll
        for (int i = 0; i < 4; ++i) {
            int c = i * 256 + tid;                   // 1024 chunks of 8 u16
            int row = c >> 4, c8 = c & 15;
            if (m0 + row < M)
                *(int4*)(C + (size_t)(m0 + row) * 256 + h * 128 + c8 * 8) =
                    *(const int4*)(lds + c * 8);
        }
        __syncthreads();
    }
}

// ---------------- fused bucket-scatter || gemm1 ----------------

__global__ __launch_bounds__(256) void gemm1_scatter_kernel(
    const float* __restrict__ x, const u16* __restrict__ W1T, u16* __restrict__ S1,
    const int* __restrict__ esrc, const int* __restrict__ edst,
    const float* __restrict__ ew, int* __restrict__ fill, u64* __restrict__ region) {
    __shared__ __align__(16) u16 lds[8192];          // 16KB: A dbuf / epilogue scratch
    int b = blockIdx.x;
    int tid = threadIdx.x;
    if (b < SCB) {
        int* cnt  = (int*)lds;          // [196]
        int* base = cnt + NBUCK;        // [196]
        if (tid < NBUCK) cnt[tid] = 0;
        __syncthreads();
        int e0 = b * 2048 + tid * 8;
        int d[8], s[8], rk[8];
        float w[8];
        bool act = (e0 < N_EDGES);      // partial tail block: full 8-chunks only
        if (act) {
            int4 d0 = *(const int4*)(edst + e0),  d1 = *(const int4*)(edst + e0 + 4);
            int4 s0 = *(const int4*)(esrc + e0),  s1 = *(const int4*)(esrc + e0 + 4);
            float4 w0 = *(const float4*)(ew + e0), w1 = *(const float4*)(ew + e0 + 4);
            d[0]=d0.x; d[1]=d0.y; d[2]=d0.z; d[3]=d0.w;
            d[4]=d1.x; d[5]=d1.y; d[6]=d1.z; d[7]=d1.w;
            s[0]=s0.x; s[1]=s0.y; s[2]=s0.z; s[3]=s0.w;
            s[4]=s1.x; s[5]=s1.y; s[6]=s1.z; s[7]=s1.w;
            w[0]=w0.x; w[1]=w0.y; w[2]=w0.z; w[3]=w0.w;
            w[4]=w1.x; w[5]=w1.y; w[6]=w1.z; w[7]=w1.w;
            #pragma unroll
            for (int i = 0; i < 8; ++i)
                rk[i] = atomicAdd(&cnt[d[i] >> 8], 1);   // LDS atomic: block-local rank
        }
        __syncthreads();
        if (tid < NBUCK) base[tid] = atomicAdd(&fill[tid], cnt[tid]);
        __syncthreads();
        if (act) {
            #pragma unroll
            for (int i = 0; i < 8; ++i) {
                int g = d[i] >> 8;
                int pos = base[g] + rk[i];
                if (pos < BCAP) {
                    u64 en = ((u64)(d[i] & 255) << 32) |
                             (u64)((u32)s[i] | ((u32)f2bf(w[i]) << 16));
                    region[(size_t)g * BCAP + pos] = en;
                }
            }
        }
    } else {
        gemm1_body(x, W1T, S1, N_NODES, b - SCB, lds);
    }
}

// ---------------- gemm2: S2[M,64] = H[M,256] @ W2T[64][256]^T ----------------
// A (H) async16 double-buffered (2x8192 u16); B frags direct from L2.

__global__ __launch_bounds__(256) void gemm2_kernel(const u16* __restrict__ H,
                                                    const u16* __restrict__ W2T,
                                                    u16* __restrict__ S2, int M) {
    __shared__ __align__(16) u16 lds[16384];         // 32KB: A dbuf / scratch
    const int tid = threadIdx.x;
    const int wv = tid >> 6, lane = tid & 63;
    const int wrow = wv >> 1, wcol = wv & 1;         // 2x2 waves
    const int lm = lane & 15, quad = lane >> 4;
    const int m0 = blockIdx.x * 128;
    const int co0 = ((0 * 4 + quad) ^ (lm & 7)) * 8;
    const int co1 = ((1 * 4 + quad) ^ (lm & 7)) * 8;

    f32x4 acc[4][2];
    #pragma unroll
    for (int r = 0; r < 4; ++r)
        #pragma unroll
        for (int c = 0; c < 2; ++c) acc[r][c] = (f32x4){0.f, 0.f, 0.f, 0.f};

    // staging geometry: 4 async16/thread per tile
    auto stage = [&](u16* dst, int t) {
        #pragma unroll
        for (int i = 0; i < 4; ++i) {
            int c = i * 256 + tid;
            int row = c >> 3, kb = c & 7;
            int gr = m0 + row; if (gr > M - 1) gr = M - 1;
            async16(H + (size_t)gr * NHID + t * 64 + ((kb ^ (row & 7)) * 8), dst + c * 8);
        }
    };

    stage(lds, 0);
    __syncthreads();

    for (int t = 0; t < 4; ++t) {
        u16* As = lds + (t & 1) * 8192;
        if (t + 1 < 4) stage(lds + ((t + 1) & 1) * 8192, t + 1);
        #pragma unroll
        for (int kk = 0; kk < 2; ++kk) {
            const int co = kk ? co1 : co0;
            bf16x8 af[4], bfv[2];
            #pragma unroll
            for (int rt = 0; rt < 4; ++rt)
                af[rt] = *(const bf16x8*)(As + (wrow * 64 + rt * 16 + lm) * 64 + co);
            #pragma unroll
            for (int ct = 0; ct < 2; ++ct) {
                int n = wcol * 32 + ct * 16 + lm;
                bfv[ct] = *(const bf16x8*)(W2T + (size_t)n * NHID + t * 64 + kk * 32 + quad * 8);
            }
            #pragma unroll
            for (int rt = 0; rt < 4; ++rt)
                #pragma unroll
                for (int ct = 0; ct < 2; ++ct)
                    acc[rt][ct] = __builtin_amdgcn_mfma_f32_16x16x32_bf16(
                        af[rt], bfv[ct], acc[rt][ct], 0, 0, 0);
        }
        __syncthreads();
    }

    // epilogue: full repack through scratch [128][64]
    #pragma unroll
    for (int rt = 0; rt < 4; ++rt)
        #pragma unroll
        for (int ct = 0; ct < 2; ++ct) {
            int col = wcol * 32 + ct * 16 + lm;
            #pragma unroll
            for (int r = 0; r < 4; ++r)
                lds[(wrow * 64 + rt * 16 + quad * 4 + r) * 64 + col] = f2bf(acc[rt][ct][r]);
        }
    __syncthreads();
    #pragma unroll
    for (int i = 0; i < 4; ++i) {
        int c = i * 256 + tid;
        int row = c >> 3;
        if (m0 + row < M)
            *(int4*)(S2 + (size_t)m0 * 64 + c * 8) = *(const int4*)(lds + c * 8);
    }
}

// ---------------- csr_sort: per-bucket LDS counting-rank -> fixed-stride csr ----------------

__global__ __launch_bounds__(256) void csr_sort_kernel(
    const u64* __restrict__ region, const int* __restrict__ fill,
    u32* __restrict__ csr, int* __restrict__ deg) {
    __shared__ int cnt2[256];
    int b = blockIdx.x, tid = threadIdx.x;
    cnt2[tid] = 0;
    __syncthreads();
    int Eb = fill[b]; if (Eb > BCAP) Eb = BCAP;
    for (int i = tid; i < Eb; i += 256) {
        u64 en = region[(size_t)b * BCAP + i];
        int dlo = (int)(en >> 32) & 255;
        int r = atomicAdd(&cnt2[dlo], 1);
        if (r < CSTRIDE)
            csr[(size_t)(b * 256 + dlo) * CSTRIDE + r] = (u32)en;
    }
    __syncthreads();
    int node = b * 256 + tid;
    if (node < N_NODES) {
        int dg = cnt2[tid]; if (dg > CSTRIDE) dg = CSTRIDE;
        deg[node] = dg;
    }
}

// ---------------- fused SpMM1 + bias + ReLU + gemm2-A-build ----------------
// Block = 4 waves = 16 nodes. Phase 1: 16-deep batched gathers -> bias+relu ->
// bf16 H-row to swizzled LDS. Phase 2: 16x64x256 MFMA, B direct from L2.

__global__ __launch_bounds__(256) void spmm1_gemm2_kernel(
    const u16* __restrict__ S, const int* __restrict__ deg,
    const u32* __restrict__ csr, const float* __restrict__ bias1,
    const u16* __restrict__ W2T, u16* __restrict__ S2) {
    __shared__ __align__(16) u16 Hs[16 * 256];   // [16][256] swizzled; reused for S2 repack

    const int tid  = threadIdx.x;
    const int wv   = tid >> 6, lane = tid & 63;
    const int lm   = lane & 15, quad = lane >> 4;
    const int b    = blockIdx.x;

    float4 bv = *(const float4*)(bias1 + lane * 4);

    // ---- phase 1: gather 4 nodes per wave, 16 loads in flight ----
    #pragma unroll
    for (int it = 0; it < 4; ++it) {
        int lrow = wv * 4 + it;
        int node = __builtin_amdgcn_readfirstlane(b * 16 + lrow);
        int beg = node * CSTRIDE;
        int end = beg + deg[node];
        float a0 = 0.f, a1 = 0.f, a2 = 0.f, a3 = 0.f;
        int j = beg;
        for (; j + 16 <= end; j += 16) {
            u32 e[16];
            #pragma unroll
            for (int i = 0; i < 16; ++i) e[i] = csr[j + i];   // uniform -> s_load
            ushort4 v[16];
            #pragma unroll
            for (int i = 0; i < 16; ++i)
                v[i] = *(const ushort4*)(S + (size_t)(e[i] & 0xFFFFu) * NHID + lane * 4);
            #pragma unroll
            for (int i = 0; i < 16; ++i) {
                float w = bf2f((u16)(e[i] >> 16));
                a0 += w * bf2f(v[i].x); a1 += w * bf2f(v[i].y);
                a2 += w * bf2f(v[i].z); a3 += w * bf2f(v[i].w);
            }
        }
        for (; j + 8 <= end; j += 8) {
            u32 e[8];
            #pragma unroll
            for (int i = 0; i < 8; ++i) e[i] = csr[j + i];
            ushort4 v[8];
            #pragma unroll
            for (int i = 0; i < 8; ++i)
                v[i] = *(const ushort4*)(S + (size_t)(e[i] & 0xFFFFu) * NHID + lane * 4);
            #pragma unroll
            for (int i = 0; i < 8; ++i) {
                float w = bf2f((u16)(e[i] >> 16));
                a0 += w * bf2f(v[i].x); a1 += w * bf2f(v[i].y);
                a2 += w * bf2f(v[i].z); a3 += w * bf2f(v[i].w);
            }
        }
        for (; j < end; ++j) {
            u32 e0 = csr[j];
            float w = bf2f((u16)(e0 >> 16));
            ushort4 v0 = *(const ushort4*)(S + (size_t)(e0 & 0xFFFFu) * NHID + lane * 4);
            a0 += w * bf2f(v0.x); a1 += w * bf2f(v0.y);
            a2 += w * bf2f(v0.z); a3 += w * bf2f(v0.w);
        }
        a0 = fmaxf(a0 + bv.x, 0.f);
        a1 = fmaxf(a1 + bv.y, 0.f);
        a2 = fmaxf(a2 + bv.z, 0.f);
        a3 = fmaxf(a3 + bv.w, 0.f);
        int ch = (lane >> 1) ^ (lrow & 7);
        u32* dp = (u32*)(Hs + lrow * 256 + ch * 8 + (lane & 1) * 4);
        dp[0] = pk2(a0, a1);
        dp[1] = pk2(a2, a3);
    }
    __syncthreads();

    // ---- phase 2: S2[16][64] = H[16][256] @ W2T^T, B direct from L2 ----
    f32x4 acc = (f32x4){0.f, 0.f, 0.f, 0.f};
    #pragma unroll
    for (int k0 = 0; k0 < NHID; k0 += 64) {
        #pragma unroll
        for (int kk = 0; kk < 2; ++kk) {
            int ca = ((k0 >> 3) + kk * 4 + quad) ^ (lm & 7);
            bf16x8 af = *(const bf16x8*)(Hs + lm * 256 + ca * 8);
            int n = wv * 16 + lm;
            bf16x8 bf = *(const bf16x8*)(W2T + (size_t)n * NHID + k0 + kk * 32 + quad * 8);
            acc = __builtin_amdgcn_mfma_f32_16x16x32_bf16(af, bf, acc, 0, 0, 0);
        }
    }
    __syncthreads();

    // ---- epilogue: repack through LDS, linear store ----
    #pragma unroll
    for (int r = 0; r < 4; ++r) {
        int row = quad * 4 + r;                  // C/D: row = quad*4 + reg
        Hs[row * 64 + wv * 16 + lm] = f2bf(acc[r]);
    }
    __syncthreads();
    *(ushort4*)(S2 + (size_t)b * 1024 + tid * 4) = *(const ushort4*)(Hs + tid * 4);
}

// ---------------- SpMM2 + bias + log_softmax (one wave/node, 16-deep) ----------------

__global__ __launch_bounds__(256) void spmm_bias_lsm_kernel(
    const u16* __restrict__ S, const int* __restrict__ deg,
    const u32* __restrict__ csr, const float* __restrict__ bias,
    float* __restrict__ out, int n) {
    int node = blockIdx.x * 4 + (threadIdx.x >> 6);
    if (node >= n) return;
    node = __builtin_amdgcn_readfirstlane(node);
    int lane = threadIdx.x & 63;
    int beg = node * CSTRIDE;
    int end = beg + deg[node];
    float acc = 0.f;
    int j = beg;
    for (; j + 16 <= end; j += 16) {
        u32 e[16];
        #pragma unroll
        for (int i = 0; i < 16; ++i) e[i] = csr[j + i];   // uniform -> s_load
        u16 v[16];
        #pragma unroll
        for (int i = 0; i < 16; ++i)
            v[i] = S[(size_t)(e[i] & 0xFFFFu) * NCLASS + lane];
        #pragma unroll
        for (int i = 0; i < 16; ++i)
            acc += bf2f((u16)(e[i] >> 16)) * bf2f(v[i]);
    }
    for (; j + 8 <= end; j += 8) {
        u32 e[8];
        #pragma unroll
        for (int i = 0; i < 8; ++i) e[i] = csr[j + i];
        u16 v[8];
        #pragma unroll
        for (int i = 0; i < 8; ++i)
            v[i] = S[(size_t)(e[i] & 0xFFFFu) * NCLASS + lane];
        #pragma unroll
        for (int i = 0; i < 8; ++i)
            acc += bf2f((u16)(e[i] >> 16)) * bf2f(v[i]);
    }
    for (; j < end; ++j) {
        u32 e0 = csr[j];
        acc += bf2f((u16)(e0 >> 16)) * bf2f(S[(size_t)(e0 & 0xFFFFu) * NCLASS + lane]);
    }

    float x = acc + bias[lane];
    float m = x;
    #pragma unroll
    for (int off = 32; off > 0; off >>= 1) m = fmaxf(m, __shfl_xor(m, off));
    float e = expf(x - m);
    float ssum = e;
    #pragma unroll
    for (int off = 32; off > 0; off >>= 1) ssum += __shfl_xor(ssum, off);
    out[(size_t)node * NCLASS + lane] = x - m - logf(ssum);
}

// ---------------- launch ----------------

extern "C" void kernel_launch(void* const* d_in, const int* in_sizes, int n_in,
                              void* d_out, int out_size, void* d_ws, size_t ws_size,
                              hipStream_t stream) {
    const float* x  = (const float*)d_in[0];   // [50000,512]
    const float* W1 = (const float*)d_in[1];   // [512,256]
    const float* b1 = (const float*)d_in[2];   // [256]
    const float* W2 = (const float*)d_in[3];   // [256,64]
    const float* b2 = (const float*)d_in[4];   // [64]
    const float* ew = (const float*)d_in[5];   // [800000]
    const int* esrc = (const int*)d_in[6];
    const int* edst = (const int*)d_in[7];
    float* out = (float*)d_out;                // [50000,64]

    char* ws = (char*)d_ws;
    size_t off = 0;
    auto take = [&](size_t bytes) -> void* {
        off = (off + 255) & ~(size_t)255;
        void* p = ws + off;
        off += bytes;
        return p;
    };
    u16* S1   = (u16*)take((size_t)N_NODES * NHID * 2);          // 25.6 MB
    u16* S2   = (u16*)take((size_t)N_NODES * NCLASS * 2);        // 6.4 MB
    u16* W1T  = (u16*)take((size_t)NHID * NFEAT * 2);            // [256][512]
    u16* W2T  = (u16*)take((size_t)NCLASS * NHID * 2);           // [64][256]
    int* deg  = (int*)take((size_t)N_NODES * 4);                 // 0.2 MB
    u32* csr  = (u32*)take((size_t)N_NODES * CSTRIDE * 4);       // 12.8 MB fixed-stride
    int* fill = (int*)take((size_t)NBUCK * 4);
    u64* region = (u64*)take((size_t)NBUCK * BCAP * 8);          // 8.03 MB
    (void)ws_size; (void)in_sizes; (void)n_in; (void)out_size;

    prep0_kernel<<<PW1B + PW2B + 1, 256, 0, stream>>>(W1, W1T, W2, W2T, fill);
    gemm1_scatter_kernel<<<SCB + GB1, 256, 0, stream>>>(x, W1T, S1, esrc, edst, ew,
                                                        fill, region);
    csr_sort_kernel<<<NBUCK, 256, 0, stream>>>(region, fill, csr, deg);
    spmm1_gemm2_kernel<<<FNB, 256, 0, stream>>>(S1, deg, csr, b1, W2T, S2);
    spmm_bias_lsm_kernel<<<(N_NODES + 3) / 4, 256, 0, stream>>>(
        S2, deg, csr, b2, out, N_NODES);
}

// Round 8
// 288.584 us; speedup vs baseline: 1.0484x; 1.0484x over previous
//
#include <hip/hip_runtime.h>
#include <cstdint>

// GCN forward on MI355X (gfx950). f32 in/out; bf16 MFMA with fp32 accum;
// bf16 intermediates; 4-byte packed fixed-stride CSR (src:u16 | weight:bf16).
// Round 17: dependency-repacked chain; gemm reverted to R15 structure.
//  - R16's B-direct-from-L2 regressed (-10us): L2 latency exposed before every
//    MFMA. gemm1 back to async16-staged A+B (R15 gemm_body, 67.7us fused).
//  - fill zeroing -> hipMemsetAsync. Dispatch1 = bucketA (1.6KB LDS, full
//    occupancy) || W-transposes. Dispatch2 = gemm1 || csr_sort (csr_sort only
//    needs dispatch1; hides under gemm). 4 kernels + memset.
//  - spmm kernels keep R16 improvements (Hs-only LDS, 16-deep gathers).
// Chain: memset(fill) -> [bucketA || Wtranspose] -> [gemm1 || csr_sort]
//   -> spmm1+bias+relu+gemm2 -> spmm2+bias+log_softmax.

typedef unsigned short u16;
typedef unsigned int u32;
typedef unsigned long long u64;
typedef __attribute__((ext_vector_type(8))) short bf16x8;
typedef __attribute__((ext_vector_type(4))) float f32x4;

#define N_NODES 50000
#define N_EDGES 800000
#define NFEAT 512
#define NHID 256
#define NCLASS 64
#define CSTRIDE 64        // fixed CSR slots per node (max deg << 64)

#define NBUCK 196         // coarse buckets: dst>>8 (50000/256)
#define BCAP 5120         // bucket region capacity (mean 4096 + 16 sigma)
#define SCB 391           // bucket-scatter blocks: ceil(800000/2048)
#define GB1 782           // gemm1 blocks: ceil(50000/64)
#define PW1B 512          // W1T transpose blocks
#define PW2B 64           // W2T transpose blocks
#define FNB 3125          // fused spmm1+gemm2 blocks: 50000/16

__device__ __forceinline__ float bf2f(u16 h) {
    union { u32 u; float f; } c; c.u = ((u32)h) << 16; return c.f;
}
__device__ __forceinline__ u16 f2bf(float f) {
    union { float f; u32 u; } c; c.f = f;
    u32 u = c.u;
    return (u16)((u + 0x7fffu + ((u >> 16) & 1u)) >> 16);   // RNE
}
__device__ __forceinline__ u32 pk2(float a, float b) {
    return (u32)f2bf(a) | ((u32)f2bf(b) << 16);
}

// async global->LDS, 16B per lane; LDS dest = wave-uniform base + lane*16.
__device__ __forceinline__ void async16(const void* g, void* l) {
    __builtin_amdgcn_global_load_lds(
        (const __attribute__((address_space(1))) void*)(uintptr_t)g,
        (__attribute__((address_space(3))) void*)(uintptr_t)l, 16, 0, 0);
}

// ---------------- dispatch 1: bucketA scatter || W1/W2 transpose+cvt ----------------
// blocks [0,SCB): 2048 edges/block; LDS-rank over 196 buckets (dst>>8), one
// global atomicAdd per (block,bucket), u64 entries -> static bucket regions.
// [SCB,SCB+PW1B): W1T. [SCB+PW1B,SCB+PW1B+PW2B): W2T. LDS only 1.6KB.

__global__ __launch_bounds__(256) void prep_scatter_kernel(
    const float* __restrict__ W1, u16* __restrict__ W1T,
    const float* __restrict__ W2, u16* __restrict__ W2T,
    const int* __restrict__ esrc, const int* __restrict__ edst,
    const float* __restrict__ ew, int* __restrict__ fill, u64* __restrict__ region) {
    __shared__ int cnt[NBUCK];
    __shared__ int base[NBUCK];
    int b = blockIdx.x, tid = threadIdx.x;
    if (b < SCB) {
        if (tid < NBUCK) cnt[tid] = 0;
        __syncthreads();
        int e0 = b * 2048 + tid * 8;
        int d[8], s[8], rk[8];
        float w[8];
        bool act = (e0 < N_EDGES);      // partial tail block: full 8-chunks only
        if (act) {
            int4 d0 = *(const int4*)(edst + e0),  d1 = *(const int4*)(edst + e0 + 4);
            int4 s0 = *(const int4*)(esrc + e0),  s1 = *(const int4*)(esrc + e0 + 4);
            float4 w0 = *(const float4*)(ew + e0), w1 = *(const float4*)(ew + e0 + 4);
            d[0]=d0.x; d[1]=d0.y; d[2]=d0.z; d[3]=d0.w;
            d[4]=d1.x; d[5]=d1.y; d[6]=d1.z; d[7]=d1.w;
            s[0]=s0.x; s[1]=s0.y; s[2]=s0.z; s[3]=s0.w;
            s[4]=s1.x; s[5]=s1.y; s[6]=s1.z; s[7]=s1.w;
            w[0]=w0.x; w[1]=w0.y; w[2]=w0.z; w[3]=w0.w;
            w[4]=w1.x; w[5]=w1.y; w[6]=w1.z; w[7]=w1.w;
            #pragma unroll
            for (int i = 0; i < 8; ++i)
                rk[i] = atomicAdd(&cnt[d[i] >> 8], 1);   // LDS atomic: block-local rank
        }
        __syncthreads();
        if (tid < NBUCK) base[tid] = atomicAdd(&fill[tid], cnt[tid]);
        __syncthreads();
        if (act) {
            #pragma unroll
            for (int i = 0; i < 8; ++i) {
                int g = d[i] >> 8;
                int pos = base[g] + rk[i];
                if (pos < BCAP) {
                    u64 en = ((u64)(d[i] & 255) << 32) |
                             (u64)((u32)s[i] | ((u32)f2bf(w[i]) << 16));
                    region[(size_t)g * BCAP + pos] = en;
                }
            }
        }
    } else if (b < SCB + PW1B) {
        int idx = (b - SCB) * 256 + tid;           // W1T[256][512]
        int n = idx >> 9, k = idx & 511;
        W1T[idx] = f2bf(W1[(size_t)k * NHID + n]);
    } else {
        int idx = (b - SCB - PW1B) * 256 + tid;    // W2T[64][256]
        int n = idx >> 8, k = idx & 255;
        W2T[idx] = f2bf(W2[(size_t)k * NCLASS + n]);
    }
}

// ---------------- gemm body (R15): C[M,NT] = A[M,K] @ BT[NT][K]^T ----------------
// Tiles in LDS are [row][64] u16 with the 16B-chunk index XOR-swizzled by row&7
// (T2). Async-staged B keeps LDS dest linear and permutes the global source
// chunk; the reg-staged (ACVT) A swizzles the ds_write address. Fragment reads
// apply the same XOR. 4 waves 1x4, BK=64 (2 k-halves). LDS epilogue repack.

template <int MT, int NT, int WCOLS, int K, bool ACVT>
__device__ __forceinline__ void gemm_body(const void* __restrict__ Av,
                                          const u16* __restrict__ BT,
                                          u16* __restrict__ C, int M,
                                          int bid, u16* lds) {
    constexpr int WROWS = 4 / WCOLS;
    constexpr int RT = MT / (16 * WROWS);
    constexpr int CT = NT / (16 * WCOLS);
    u16* As = lds;             // [MT][64] swizzled
    u16* Bs = lds + MT * 64;   // [NT][64] swizzled (B^T: row n, k-contig)

    const int tid  = threadIdx.x;
    const int wv   = tid >> 6, lane = tid & 63;
    const int lm   = lane & 15, quad = lane >> 4;
    const int wrow = wv / WCOLS, wcol = wv % WCOLS;
    const int m0   = bid * MT;
    const int co0 = ((0 * 4 + quad) ^ (lm & 7)) * 8;
    const int co1 = ((1 * 4 + quad) ^ (lm & 7)) * 8;

    f32x4 acc[RT][CT];
    #pragma unroll
    for (int r = 0; r < RT; ++r)
        #pragma unroll
        for (int c = 0; c < CT; ++c) acc[r][c] = (f32x4){0.f, 0.f, 0.f, 0.f};

    for (int k0 = 0; k0 < K; k0 += 64) {
        if constexpr (ACVT) {
            static_assert(MT == 64, "ACVT staging assumes MT==64 (16 elems/thread)");
            const float* Af = (const float*)Av;
            // issue A f32 loads first (reg), then B DMA, then pack+write.
            int row = tid >> 2, ko = (tid & 3) * 16;   // ko: u16 offset, chunks 2q,2q+1
            int gr = m0 + row; if (gr > M - 1) gr = M - 1;
            const float4* gp = (const float4*)(Af + (size_t)gr * K + k0 + ko);
            float4 f0 = gp[0], f1 = gp[1], f2 = gp[2], f3 = gp[3];
            #pragma unroll
            for (int i = 0; i < NT / 32; ++i) {
                int c = i * 256 + tid;
                int n = c >> 3, kb = c & 7;
                async16(BT + (size_t)n * K + k0 + ((kb ^ (n & 7)) * 8), Bs + c * 8);
            }
            u32 p[8] = {pk2(f0.x, f0.y), pk2(f0.z, f0.w), pk2(f1.x, f1.y), pk2(f1.z, f1.w),
                        pk2(f2.x, f2.y), pk2(f2.z, f2.w), pk2(f3.x, f3.y), pk2(f3.z, f3.w)};
            int ch0 = (2 * (tid & 3))     ^ (row & 7);
            int ch1 = (2 * (tid & 3) + 1) ^ (row & 7);
            *(int4*)(As + row * 64 + ch0 * 8) = *(int4*)&p[0];
            *(int4*)(As + row * 64 + ch1 * 8) = *(int4*)&p[4];
        } else {
            const u16* A = (const u16*)Av;
            #pragma unroll
            for (int i = 0; i < NT / 32; ++i) {
                int c = i * 256 + tid;
                int n = c >> 3, kb = c & 7;
                async16(BT + (size_t)n * K + k0 + ((kb ^ (n & 7)) * 8), Bs + c * 8);
            }
            #pragma unroll
            for (int i = 0; i < MT / 32; ++i) {
                int c = i * 256 + tid;
                int row = c >> 3, kb = c & 7;
                int gr = m0 + row; if (gr > M - 1) gr = M - 1;
                async16(A + (size_t)gr * K + k0 + ((kb ^ (row & 7)) * 8), As + c * 8);
            }
        }
        __syncthreads();   // drains async vmcnt + lgkm (ds_write)

        #pragma unroll
        for (int kk = 0; kk < 2; ++kk) {
            const int co = kk ? co1 : co0;
            bf16x8 af[RT], bfv[CT];
            #pragma unroll
            for (int rt = 0; rt < RT; ++rt) {
                int row = wrow * (RT * 16) + rt * 16 + lm;
                af[rt] = *(const bf16x8*)(As + row * 64 + co);
            }
            #pragma unroll
            for (int ct = 0; ct < CT; ++ct) {
                int n = wcol * CT * 16 + ct * 16 + lm;
                bfv[ct] = *(const bf16x8*)(Bs + n * 64 + co);
            }
            #pragma unroll
            for (int rt = 0; rt < RT; ++rt)
                #pragma unroll
                for (int ct = 0; ct < CT; ++ct)
                    acc[rt][ct] = __builtin_amdgcn_mfma_f32_16x16x32_bf16(
                        af[rt], bfv[ct], acc[rt][ct], 0, 0, 0);
        }
        __syncthreads();
    }

    #pragma unroll
    for (int rt = 0; rt < RT; ++rt)
        #pragma unroll
        for (int ct = 0; ct < CT; ++ct) {
            int col = wcol * CT * 16 + ct * 16 + lm;
            #pragma unroll
            for (int r = 0; r < 4; ++r) {
                int row = wrow * (RT * 16) + rt * 16 + quad * 4 + r;  // C/D: row=quad*4+reg
                lds[row * NT + col] = f2bf(acc[rt][ct][r]);
            }
        }
    __syncthreads();
    constexpr int NC = MT * NT / 2048;
    #pragma unroll
    for (int i = 0; i < NC; ++i) {
        int c = i * 256 + tid;
        int row = (c * 8) / NT;
        if (m0 + row < M)
            *(int4*)(C + (size_t)m0 * NT + c * 8) = *(const int4*)(lds + c * 8);
    }
}

// ---------------- dispatch 2: gemm1 || csr_sort ----------------
// blocks [0,NBUCK): per-bucket LDS counting-rank -> fixed-stride csr + deg
// (needs only dispatch 1). blocks [NBUCK,NBUCK+GB1): gemm1 on f32 x.

__global__ __launch_bounds__(256) void gemm1_sort_kernel(
    const float* __restrict__ x, const u16* __restrict__ W1T, u16* __restrict__ S1,
    const u64* __restrict__ region, const int* __restrict__ fill,
    u32* __restrict__ csr, int* __restrict__ deg) {
    __shared__ __align__(16) u16 lds[(64 + 256) * 64];   // 40KB
    int b = blockIdx.x, tid = threadIdx.x;
    if (b < NBUCK) {
        int* cnt2 = (int*)lds;          // [256]
        cnt2[tid] = 0;
        __syncthreads();
        int Eb = fill[b]; if (Eb > BCAP) Eb = BCAP;
        for (int i = tid; i < Eb; i += 256) {
            u64 en = region[(size_t)b * BCAP + i];
            int dlo = (int)(en >> 32) & 255;
            int r = atomicAdd(&cnt2[dlo], 1);
            if (r < CSTRIDE)
                csr[(size_t)(b * 256 + dlo) * CSTRIDE + r] = (u32)en;
        }
        __syncthreads();
        int node = b * 256 + tid;
        if (node < N_NODES) {
            int dg = cnt2[tid]; if (dg > CSTRIDE) dg = CSTRIDE;
            deg[node] = dg;
        }
    } else {
        gemm_body<64, 256, 4, NFEAT, true>(x, W1T, S1, N_NODES, b - NBUCK, lds);
    }
}

// ---------------- fused SpMM1 + bias + ReLU + gemm2 ----------------
// Block = 4 waves = 16 nodes. Phase 1: 16-deep batched gathers -> bias+relu ->
// bf16 H-row to swizzled LDS. Phase 2: 16x64x256 MFMA, B direct from L2.
// LDS only 8KB -> high occupancy for gather latency hiding.

__global__ __launch_bounds__(256) void spmm1_gemm2_kernel(
    const u16* __restrict__ S, const int* __restrict__ deg,
    const u32* __restrict__ csr, const float* __restrict__ bias1,
    const u16* __restrict__ W2T, u16* __restrict__ S2) {
    __shared__ __align__(16) u16 Hs[16 * 256];   // [16][256] swizzled; reused for repack

    const int tid  = threadIdx.x;
    const int wv   = tid >> 6, lane = tid & 63;
    const int lm   = lane & 15, quad = lane >> 4;
    const int b    = blockIdx.x;

    float4 bv = *(const float4*)(bias1 + lane * 4);

    // ---- phase 1: gather 4 nodes per wave, 16 loads in flight ----
    #pragma unroll
    for (int it = 0; it < 4; ++it) {
        int lrow = wv * 4 + it;
        int node = __builtin_amdgcn_readfirstlane(b * 16 + lrow);
        int beg = node * CSTRIDE;
        int end = beg + deg[node];
        float a0 = 0.f, a1 = 0.f, a2 = 0.f, a3 = 0.f;
        int j = beg;
        for (; j + 16 <= end; j += 16) {
            u32 e[16];
            #pragma unroll
            for (int i = 0; i < 16; ++i) e[i] = csr[j + i];   // uniform -> s_load
            ushort4 v[16];
            #pragma unroll
            for (int i = 0; i < 16; ++i)
                v[i] = *(const ushort4*)(S + (size_t)(e[i] & 0xFFFFu) * NHID + lane * 4);
            #pragma unroll
            for (int i = 0; i < 16; ++i) {
                float w = bf2f((u16)(e[i] >> 16));
                a0 += w * bf2f(v[i].x); a1 += w * bf2f(v[i].y);
                a2 += w * bf2f(v[i].z); a3 += w * bf2f(v[i].w);
            }
        }
        for (; j + 8 <= end; j += 8) {
            u32 e[8];
            #pragma unroll
            for (int i = 0; i < 8; ++i) e[i] = csr[j + i];
            ushort4 v[8];
            #pragma unroll
            for (int i = 0; i < 8; ++i)
                v[i] = *(const ushort4*)(S + (size_t)(e[i] & 0xFFFFu) * NHID + lane * 4);
            #pragma unroll
            for (int i = 0; i < 8; ++i) {
                float w = bf2f((u16)(e[i] >> 16));
                a0 += w * bf2f(v[i].x); a1 += w * bf2f(v[i].y);
                a2 += w * bf2f(v[i].z); a3 += w * bf2f(v[i].w);
            }
        }
        for (; j < end; ++j) {
            u32 e0 = csr[j];
            float w = bf2f((u16)(e0 >> 16));
            ushort4 v0 = *(const ushort4*)(S + (size_t)(e0 & 0xFFFFu) * NHID + lane * 4);
            a0 += w * bf2f(v0.x); a1 += w * bf2f(v0.y);
            a2 += w * bf2f(v0.z); a3 += w * bf2f(v0.w);
        }
        a0 = fmaxf(a0 + bv.x, 0.f);
        a1 = fmaxf(a1 + bv.y, 0.f);
        a2 = fmaxf(a2 + bv.z, 0.f);
        a3 = fmaxf(a3 + bv.w, 0.f);
        int ch = (lane >> 1) ^ (lrow & 7);
        u32* dp = (u32*)(Hs + lrow * 256 + ch * 8 + (lane & 1) * 4);
        dp[0] = pk2(a0, a1);
        dp[1] = pk2(a2, a3);
    }
    __syncthreads();

    // ---- phase 2: S2[16][64] = H[16][256] @ W2T^T, B direct from L2 ----
    f32x4 acc = (f32x4){0.f, 0.f, 0.f, 0.f};
    #pragma unroll
    for (int k0 = 0; k0 < NHID; k0 += 64) {
        #pragma unroll
        for (int kk = 0; kk < 2; ++kk) {
            int ca = ((k0 >> 3) + kk * 4 + quad) ^ (lm & 7);
            bf16x8 af = *(const bf16x8*)(Hs + lm * 256 + ca * 8);
            int n = wv * 16 + lm;
            bf16x8 bf = *(const bf16x8*)(W2T + (size_t)n * NHID + k0 + kk * 32 + quad * 8);
            acc = __builtin_amdgcn_mfma_f32_16x16x32_bf16(af, bf, acc, 0, 0, 0);
        }
    }
    __syncthreads();

    // ---- epilogue: repack through LDS, linear store ----
    #pragma unroll
    for (int r = 0; r < 4; ++r) {
        int row = quad * 4 + r;                  // C/D: row = quad*4 + reg
        Hs[row * 64 + wv * 16 + lm] = f2bf(acc[r]);
    }
    __syncthreads();
    *(ushort4*)(S2 + (size_t)b * 1024 + tid * 4) = *(const ushort4*)(Hs + tid * 4);
}

// ---------------- SpMM2 + bias + log_softmax (one wave/node, 16-deep) ----------------

__global__ __launch_bounds__(256) void spmm_bias_lsm_kernel(
    const u16* __restrict__ S, const int* __restrict__ deg,
    const u32* __restrict__ csr, const float* __restrict__ bias,
    float* __restrict__ out, int n) {
    int node = blockIdx.x * 4 + (threadIdx.x >> 6);
    if (node >= n) return;
    node = __builtin_amdgcn_readfirstlane(node);
    int lane = threadIdx.x & 63;
    int beg = node * CSTRIDE;
    int end = beg + deg[node];
    float acc = 0.f;
    int j = beg;
    for (; j + 16 <= end; j += 16) {
        u32 e[16];
        #pragma unroll
        for (int i = 0; i < 16; ++i) e[i] = csr[j + i];   // uniform -> s_load
        u16 v[16];
        #pragma unroll
        for (int i = 0; i < 16; ++i)
            v[i] = S[(size_t)(e[i] & 0xFFFFu) * NCLASS + lane];
        #pragma unroll
        for (int i = 0; i < 16; ++i)
            acc += bf2f((u16)(e[i] >> 16)) * bf2f(v[i]);
    }
    for (; j + 8 <= end; j += 8) {
        u32 e[8];
        #pragma unroll
        for (int i = 0; i < 8; ++i) e[i] = csr[j + i];
        u16 v[8];
        #pragma unroll
        for (int i = 0; i < 8; ++i)
            v[i] = S[(size_t)(e[i] & 0xFFFFu) * NCLASS + lane];
        #pragma unroll
        for (int i = 0; i < 8; ++i)
            acc += bf2f((u16)(e[i] >> 16)) * bf2f(v[i]);
    }
    for (; j < end; ++j) {
        u32 e0 = csr[j];
        acc += bf2f((u16)(e0 >> 16)) * bf2f(S[(size_t)(e0 & 0xFFFFu) * NCLASS + lane]);
    }

    float x = acc + bias[lane];
    float m = x;
    #pragma unroll
    for (int off = 32; off > 0; off >>= 1) m = fmaxf(m, __shfl_xor(m, off));
    float e = expf(x - m);
    float ssum = e;
    #pragma unroll
    for (int off = 32; off > 0; off >>= 1) ssum += __shfl_xor(ssum, off);
    out[(size_t)node * NCLASS + lane] = x - m - logf(ssum);
}

// ---------------- launch ----------------

extern "C" void kernel_launch(void* const* d_in, const int* in_sizes, int n_in,
                              void* d_out, int out_size, void* d_ws, size_t ws_size,
                              hipStream_t stream) {
    const float* x  = (const float*)d_in[0];   // [50000,512]
    const float* W1 = (const float*)d_in[1];   // [512,256]
    const float* b1 = (const float*)d_in[2];   // [256]
    const float* W2 = (const float*)d_in[3];   // [256,64]
    const float* b2 = (const float*)d_in[4];   // [64]
    const float* ew = (const float*)d_in[5];   // [800000]
    const int* esrc = (const int*)d_in[6];
    const int* edst = (const int*)d_in[7];
    float* out = (float*)d_out;                // [50000,64]

    char* ws = (char*)d_ws;
    size_t off = 0;
    auto take = [&](size_t bytes) -> void* {
        off = (off + 255) & ~(size_t)255;
        void* p = ws + off;
        off += bytes;
        return p;
    };
    u16* S1   = (u16*)take((size_t)N_NODES * NHID * 2);          // 25.6 MB
    u16* S2   = (u16*)take((size_t)N_NODES * NCLASS * 2);        // 6.4 MB
    u16* W1T  = (u16*)take((size_t)NHID * NFEAT * 2);            // [256][512]
    u16* W2T  = (u16*)take((size_t)NCLASS * NHID * 2);           // [64][256]
    int* deg  = (int*)take((size_t)N_NODES * 4);                 // 0.2 MB
    u32* csr  = (u32*)take((size_t)N_NODES * CSTRIDE * 4);       // 12.8 MB fixed-stride
    int* fill = (int*)take((size_t)NBUCK * 4);
    u64* region = (u64*)take((size_t)NBUCK * BCAP * 8);          // 8.03 MB
    (void)ws_size; (void)in_sizes; (void)n_in; (void)out_size;

    hipMemsetAsync(fill, 0, (size_t)NBUCK * 4, stream);
    prep_scatter_kernel<<<SCB + PW1B + PW2B, 256, 0, stream>>>(
        W1, W1T, W2, W2T, esrc, edst, ew, fill, region);
    gemm1_sort_kernel<<<NBUCK + GB1, 256, 0, stream>>>(
        x, W1T, S1, region, fill, csr, deg);
    spmm1_gemm2_kernel<<<FNB, 256, 0, stream>>>(S1, deg, csr, b1, W2T, S2);
    spmm_bias_lsm_kernel<<<(N_NODES + 3) / 4, 256, 0, stream>>>(
        S2, deg, csr, b2, out, N_NODES);
}